// Round 1
// 196.208 us; speedup vs baseline: 1.0524x; 1.0524x over previous
//
#include <hip/hip_runtime.h>
#include <hip/hip_fp16.h>

// GCN, N=50000 nodes, E=800000 edges, 128->128(relu)->64, fp32 accum.
// CSR entries are 2B (src only; norm recomputed as dis[src]*dis[v]).
// r11: (a) k_count fused into the layer-1 GEMM launch (independent work,
//      hides ~10us of count under the MFMA GEMM); (b) agg kernels
//      software-pipeline the csr index loads (prefetch batch n+1's srcs
//      while batch n's H gathers are in flight -- breaks the serial
//      csr->gather->fma chain, trip count is only ~3 so the compiler
//      cannot do this itself); (c) W2^T fp16 conversion hoisted into the
//      idle k_scan3 blocks (was re-done per agg block x3125).
// NOTE (r10 post-mortem): degree-sorted scheduling bought ~0 and its
// counting-sort perm cost 133 us (30 hot atomic addresses serialize).
// Agg kernels sit near the random-gather service floor; natural order kept.

#define Nn 50000
#define Ne 800000
#define SCAN_B ((Nn + 1023) / 1024)   // 49 blocks
#define GT ((Nn + 63) / 64)           // 782 gemm tiles
#define E2B ((Ne / 2 + 255) / 256)    // 1563 count/fill blocks

using f16x8 = _Float16 __attribute__((ext_vector_type(8)));
using f32x4 = float __attribute__((ext_vector_type(4)));

// ---------------- FUSED: layer-1 MFMA GEMM + degree count ----------------
// blocks [0, GT): H1[64 nodes, 128] = fp16(X @ W1)  (MFMA 16x16x32 f16)
// blocks [GT, GT+E2B): per-edge degree count + within-bucket rank
//   (2 edges/thread, no LDS use; hidden under the GEMM blocks).
__global__ __launch_bounds__(256) void k_gemm128_count(
    const float* __restrict__ X, const float* __restrict__ W,
    __half* __restrict__ H, const int2* __restrict__ col2,
    int* __restrict__ degi, ushort2* __restrict__ rank2) {
  __shared__ _Float16 Xs[64 * 136];        // 64 rows x (128+8 pad)
  __shared__ _Float16 Wts[128 * 136];      // transposed W1

  if ((int)blockIdx.x >= GT) {
    // ----- count path -----
    int t = ((int)blockIdx.x - GT) * 256 + threadIdx.x;
    if (t < Ne / 2) {
      int2 c = col2[t];
      unsigned short r0 = (unsigned short)atomicAdd(&degi[c.x], 1);
      unsigned short r1 = (unsigned short)atomicAdd(&degi[c.y], 1);
      ushort2 rk; rk.x = r0; rk.y = r1;
      rank2[t] = rk;
    }
    return;
  }

  // ----- gemm path -----
  const int tid = threadIdx.x;
  const int base = blockIdx.x * 64;

  {
    for (int idx4 = tid; idx4 < 32 * 128; idx4 += 256) {
      int k = idx4 >> 5;
      int c = (idx4 & 31) * 4;
      float4 wv = ((const float4*)W)[idx4];
      Wts[(c + 0) * 136 + k] = (_Float16)wv.x;
      Wts[(c + 1) * 136 + k] = (_Float16)wv.y;
      Wts[(c + 2) * 136 + k] = (_Float16)wv.z;
      Wts[(c + 3) * 136 + k] = (_Float16)wv.w;
    }
  }
  {
    for (int u = tid; u < 64 * 16; u += 256) {
      int r = u >> 4, seg = u & 15;
      int node = base + r;
      if (node >= Nn) node = Nn - 1;
      const float4* xg = (const float4*)(X + (size_t)node * 128 + seg * 8);
      float4 x0 = xg[0], x1 = xg[1];
      f16x8 hv;
      hv[0] = (_Float16)x0.x; hv[1] = (_Float16)x0.y;
      hv[2] = (_Float16)x0.z; hv[3] = (_Float16)x0.w;
      hv[4] = (_Float16)x1.x; hv[5] = (_Float16)x1.y;
      hv[6] = (_Float16)x1.z; hv[7] = (_Float16)x1.w;
      *(f16x8*)&Xs[r * 136 + seg * 8] = hv;
    }
  }
  __syncthreads();

  const int w = tid >> 6, lane = tid & 63;
  const int quad = lane >> 4, mrow = lane & 15;

  f32x4 acc[8];
  #pragma unroll
  for (int ct = 0; ct < 8; ++ct) acc[ct] = (f32x4){0.f, 0.f, 0.f, 0.f};

  #pragma unroll
  for (int ko = 0; ko < 4; ++ko) {
    f16x8 av = *(const f16x8*)&Xs[(w * 16 + mrow) * 136 + ko * 32 + quad * 8];
    #pragma unroll
    for (int ct = 0; ct < 8; ++ct) {
      f16x8 bv = *(const f16x8*)&Wts[(ct * 16 + mrow) * 136 + ko * 32 + quad * 8];
      acc[ct] = __builtin_amdgcn_mfma_f32_16x16x32_f16(av, bv, acc[ct], 0, 0, 0);
    }
  }

  #pragma unroll
  for (int ct = 0; ct < 8; ++ct) {
    #pragma unroll
    for (int r = 0; r < 4; ++r) {
      int node = base + w * 16 + quad * 4 + r;
      if (node < Nn)
        H[(size_t)node * 128 + ct * 16 + mrow] = __float2half(acc[ct][r]);
    }
  }
}

// ---------------- scan phase 1: block-local exclusive scan + dis ----------------
__global__ __launch_bounds__(1024) void k_scan1(const int* __restrict__ degi,
                                                int* __restrict__ rowptr,
                                                float* __restrict__ dis,
                                                int* __restrict__ bsum) {
  __shared__ int wsum[16];
  int tid = threadIdx.x;
  int lane = tid & 63, wid = tid >> 6;
  int i = blockIdx.x * 1024 + tid;
  int v = (i < Nn) ? degi[i] : 0;
  if (i < Nn) dis[i] = rsqrtf((float)(v + 1));   // self-loop adds 1
  int incl = v;
  #pragma unroll
  for (int off = 1; off < 64; off <<= 1) {
    int t = __shfl_up(incl, off);
    if (lane >= off) incl += t;
  }
  if (lane == 63) wsum[wid] = incl;
  __syncthreads();
  if (wid == 0) {
    int wv = (lane < 16) ? wsum[lane] : 0;
    #pragma unroll
    for (int off = 1; off < 16; off <<= 1) {
      int t = __shfl_up(wv, off);
      if (lane >= off) wv += t;
    }
    if (lane < 16) wsum[lane] = wv;  // inclusive over wave totals
  }
  __syncthreads();
  int woff = (wid > 0) ? wsum[wid - 1] : 0;
  if (i < Nn) rowptr[i] = woff + incl - v;       // block-local exclusive
  if (tid == 0) bsum[blockIdx.x] = wsum[15];     // block total
}

// ---------------- scan phase 2+3 fused (+ W2^T fp16 precompute) ----------------
// Each block scans the 49 block sums; block 1's otherwise-idle threads also
// build W2h[c][k] = fp16(W2[k][c]) once (16 KB), consumed by every agg128
// block instead of re-converting 32 KB of fp32 W2 per block (x3125).
__global__ __launch_bounds__(1024) void k_scan3(int* __restrict__ rowptr,
                                                const int* __restrict__ bsum,
                                                const float* __restrict__ W2,
                                                _Float16* __restrict__ W2h) {
  __shared__ int off_s;
  int tid = threadIdx.x;
  if (tid < 64) {
    int v = (tid < SCAN_B) ? bsum[tid] : 0;
    int incl = v;
    #pragma unroll
    for (int off = 1; off < 64; off <<= 1) {
      int t = __shfl_up(incl, off);
      if (tid >= off) incl += t;
    }
    if (tid == (int)blockIdx.x) off_s = incl - v;          // exclusive offset
    if (blockIdx.x == 0 && tid == SCAN_B - 1) rowptr[Nn] = incl;  // == Ne
  }
  __syncthreads();
  int i = blockIdx.x * 1024 + tid;
  if (i < Nn) rowptr[i] += off_s;
  if (blockIdx.x == 1) {
    // W2 fp32 [128][64] -> W2h fp16 [64][128] (transposed, unpadded)
    for (int idx4 = tid; idx4 < 2048; idx4 += 1024) {
      int k = idx4 >> 4;
      int c = (idx4 & 15) * 4;
      float4 wv = ((const float4*)W2)[idx4];
      W2h[(c + 0) * 128 + k] = (_Float16)wv.x;
      W2h[(c + 1) * 128 + k] = (_Float16)wv.y;
      W2h[(c + 2) * 128 + k] = (_Float16)wv.z;
      W2h[(c + 3) * 128 + k] = (_Float16)wv.w;
    }
  }
}

// ---------------- CSR fill: 2B src only, no atomic (2 edges/thread) ----------------
__global__ __launch_bounds__(256) void k_fill(const int2* __restrict__ row2,
                                              const int2* __restrict__ col2,
                                              const int* __restrict__ rowptr,
                                              const ushort2* __restrict__ rank2,
                                              unsigned short* __restrict__ csr) {
  int t = blockIdx.x * 256 + threadIdx.x;
  if (t >= Ne / 2) return;
  int2 r = row2[t];
  int2 c = col2[t];
  ushort2 k = rank2[t];
  csr[rowptr[c.x] + (int)k.x] = (unsigned short)r.x;
  csr[rowptr[c.y] + (int)k.y] = (unsigned short)r.y;
}

__device__ __forceinline__ float2 h2f(unsigned int u) {
  return __half22float2(*(const __half2*)&u);
}

// ---------------- FUSED: agg128(+b1, relu) -> LDS fp16 -> MFMA @ W2 -> H2 fp16 ----------------
// Stage A (agg): 4 nodes/wave, 16 lanes/node, uint4 (8 fp16 feats)/lane.
//   Software-pipelined: batch n+1's csr srcs load while batch n's gathers
//   are outstanding (all batches masked; clamped prefetch past e is benign).
// Stage B (gemm): block's 16-node x 128 tile -> LDS; wave w computes output
//   col-tile [w*16, w*16+16) via 4x mfma_f32_16x16x32_f16 against W2h (LDS).
// Nn = 50000 = 3125 * 16 exactly -> no partial blocks.
__global__ __launch_bounds__(256) void k_agg128_gemm64(
    const __half* __restrict__ H, const unsigned short* __restrict__ csr,
    const int* __restrict__ rowptr, const float* __restrict__ dis,
    const float* __restrict__ bias, const _Float16* __restrict__ W2h,
    __half* __restrict__ H2, int n) {
  __shared__ _Float16 Wts[64 * 136];   // W2 transposed: [c][k]
  __shared__ _Float16 Hs[16 * 136];    // block's 16 aggregated rows (fp16)

  const int tid = threadIdx.x;
  const int wid = tid >> 6, lane = tid & 63;
  const int sub = lane >> 4, fl = lane & 15;
  const int nb = wid * 4 + sub;                  // node-in-block [0,16)
  const int v = blockIdx.x * 16 + nb;

  // stage prebuilt W2h (fp16, 16 KB) into padded LDS: 1024 f16x8, 4/thread
  {
    const f16x8* Wq = (const f16x8*)W2h;
    for (int u = tid; u < 1024; u += 256) {
      int c = u >> 4, k8 = u & 15;
      *(f16x8*)&Wts[c * 136 + k8 * 8] = Wq[u];
    }
  }

  // ---- stage A: aggregate node v's 8 feats per lane ----
  int s = rowptr[v], e = rowptr[v + 1];
  float d = dis[v];
  float sw = d * d;                              // self-loop norm = 1/deg
  const uint4* Hq = (const uint4*)H;             // 16 uint4 per 256B row
  uint4 hv = Hq[(size_t)v * 16 + fl];
  float2 p0 = h2f(hv.x), p1 = h2f(hv.y), p2 = h2f(hv.z), p3 = h2f(hv.w);
  float a0 = p0.x * sw, a1 = p0.y * sw, a2 = p1.x * sw, a3 = p1.y * sw;
  float a4 = p2.x * sw, a5 = p2.y * sw, a6 = p3.x * sw, a7 = p3.y * sw;
  constexpr int D = 6;
  if (s < e) {
    int srcs[D];
    #pragma unroll
    for (int j = 0; j < D; ++j) {
      int idx = s + j;
      srcs[j] = csr[(idx < e) ? idx : (e - 1)];
    }
    for (int base = s; base < e; base += D) {
      uint4 q[D];
      float wd[D];
      #pragma unroll
      for (int j = 0; j < D; ++j) q[j] = Hq[(size_t)srcs[j] * 16 + fl];
      #pragma unroll
      for (int j = 0; j < D; ++j) wd[j] = dis[srcs[j]];
      int ns[D];                                 // prefetch next batch srcs
      #pragma unroll
      for (int j = 0; j < D; ++j) {
        int idx = base + D + j;
        ns[j] = csr[(idx < e) ? idx : (e - 1)];
      }
      #pragma unroll
      for (int j = 0; j < D; ++j) {
        float w = ((base + j) < e) ? wd[j] * d : 0.f;
        float2 t;
        t = h2f(q[j].x); a0 = fmaf(w, t.x, a0); a1 = fmaf(w, t.y, a1);
        t = h2f(q[j].y); a2 = fmaf(w, t.x, a2); a3 = fmaf(w, t.y, a3);
        t = h2f(q[j].z); a4 = fmaf(w, t.x, a4); a5 = fmaf(w, t.y, a5);
        t = h2f(q[j].w); a6 = fmaf(w, t.x, a6); a7 = fmaf(w, t.y, a7);
      }
      #pragma unroll
      for (int j = 0; j < D; ++j) srcs[j] = ns[j];
    }
  }
  // +b1, relu, fp16 -> LDS row nb
  {
    const float4* Bq = (const float4*)bias;
    float4 b0 = Bq[fl * 2], b1v = Bq[fl * 2 + 1];
    f16x8 hrow;
    hrow[0] = (_Float16)fmaxf(a0 + b0.x, 0.f);
    hrow[1] = (_Float16)fmaxf(a1 + b0.y, 0.f);
    hrow[2] = (_Float16)fmaxf(a2 + b0.z, 0.f);
    hrow[3] = (_Float16)fmaxf(a3 + b0.w, 0.f);
    hrow[4] = (_Float16)fmaxf(a4 + b1v.x, 0.f);
    hrow[5] = (_Float16)fmaxf(a5 + b1v.y, 0.f);
    hrow[6] = (_Float16)fmaxf(a6 + b1v.z, 0.f);
    hrow[7] = (_Float16)fmaxf(a7 + b1v.w, 0.f);
    *(f16x8*)&Hs[nb * 136 + fl * 8] = hrow;
  }
  __syncthreads();

  // ---- stage B: 16x64 = (16x128) @ (128x64), wave w -> cols [w*16, w*16+16) ----
  const int quad = lane >> 4, mrow = lane & 15;
  f32x4 acc = (f32x4){0.f, 0.f, 0.f, 0.f};
  #pragma unroll
  for (int ko = 0; ko < 4; ++ko) {
    f16x8 av = *(const f16x8*)&Hs[mrow * 136 + ko * 32 + quad * 8];
    f16x8 bv = *(const f16x8*)&Wts[(wid * 16 + mrow) * 136 + ko * 32 + quad * 8];
    acc = __builtin_amdgcn_mfma_f32_16x16x32_f16(av, bv, acc, 0, 0, 0);
  }
  #pragma unroll
  for (int r = 0; r < 4; ++r) {
    int node = blockIdx.x * 16 + quad * 4 + r;
    if (node < n)
      H2[(size_t)node * 64 + wid * 16 + mrow] = __float2half(acc[r]);
  }
}

// ---------------- aggregate 64 feats (+bias, no relu) ----------------
// 4 nodes/wave, 16 lanes/node, uint2 (4 feats) per lane; depth-8 batches,
// software-pipelined csr loads (same scheme as agg128).
__global__ __launch_bounds__(256) void k_agg64(const __half* __restrict__ H,
                                               const unsigned short* __restrict__ csr,
                                               const int* __restrict__ rowptr,
                                               const float* __restrict__ dis,
                                               const float* __restrict__ bias,
                                               float* __restrict__ Out, int n) {
  const int wid = threadIdx.x >> 6, lane = threadIdx.x & 63;
  const int sub = lane >> 4, fl = lane & 15;
  int v = blockIdx.x * 16 + wid * 4 + sub;
  if (v >= n) return;
  int s = rowptr[v], e = rowptr[v + 1];
  float d = dis[v];
  float sw = d * d;
  const uint2* Hq = (const uint2*)H;             // 16 uint2 per 128B row
  uint2 hv = Hq[(size_t)v * 16 + fl];
  float2 p0 = h2f(hv.x), p1 = h2f(hv.y);
  float a0 = p0.x * sw, a1 = p0.y * sw, a2 = p1.x * sw, a3 = p1.y * sw;
  constexpr int D = 8;
  if (s < e) {
    int srcs[D];
    #pragma unroll
    for (int j = 0; j < D; ++j) {
      int idx = s + j;
      srcs[j] = csr[(idx < e) ? idx : (e - 1)];
    }
    for (int base = s; base < e; base += D) {
      uint2 q[D];
      float wd[D];
      #pragma unroll
      for (int j = 0; j < D; ++j) q[j] = Hq[(size_t)srcs[j] * 16 + fl];
      #pragma unroll
      for (int j = 0; j < D; ++j) wd[j] = dis[srcs[j]];
      int ns[D];                                 // prefetch next batch srcs
      #pragma unroll
      for (int j = 0; j < D; ++j) {
        int idx = base + D + j;
        ns[j] = csr[(idx < e) ? idx : (e - 1)];
      }
      #pragma unroll
      for (int j = 0; j < D; ++j) {
        float w = ((base + j) < e) ? wd[j] * d : 0.f;
        float2 t;
        t = h2f(q[j].x); a0 = fmaf(w, t.x, a0); a1 = fmaf(w, t.y, a1);
        t = h2f(q[j].y); a2 = fmaf(w, t.x, a2); a3 = fmaf(w, t.y, a3);
      }
      #pragma unroll
      for (int j = 0; j < D; ++j) srcs[j] = ns[j];
    }
  }
  const float4* Bq = (const float4*)bias;
  float4 b = Bq[fl];
  float4 o = make_float4(a0 + b.x, a1 + b.y, a2 + b.z, a3 + b.w);
  ((float4*)(Out + (size_t)v * 64))[fl] = o;
}

extern "C" void kernel_launch(void* const* d_in, const int* in_sizes, int n_in,
                              void* d_out, int out_size, void* d_ws, size_t ws_size,
                              hipStream_t stream) {
  const float* x  = (const float*)d_in[0];
  const int*   ei = (const int*)d_in[1];    // [2, E] row-major
  const int*   row = ei;                    // edge_index[0] (source)
  const int*   col = ei + Ne;               // edge_index[1] (dest / segment)
  const float* W1 = (const float*)d_in[2];
  const float* b1 = (const float*)d_in[3];
  const float* W2 = (const float*)d_in[4];
  const float* b2 = (const float*)d_in[5];
  float* out = (float*)d_out;

  char* ws = (char*)d_ws;
  size_t off = 0;
  auto alloc = [&](size_t bytes) -> void* {
    void* p = ws + off;
    off += (bytes + 255) & ~(size_t)255;
    return p;
  };
  int*    degi   = (int*)   alloc(Nn * sizeof(int));       // zeroed
  int*    rowptr = (int*)   alloc((Nn + 1) * sizeof(int));
  float*  dis    = (float*) alloc(Nn * sizeof(float));
  int*    bsum   = (int*)   alloc(64 * sizeof(int));
  unsigned short* rank = (unsigned short*)alloc((size_t)Ne * sizeof(unsigned short)); // 1.6 MB
  unsigned short* csr  = (unsigned short*)alloc((size_t)Ne * sizeof(unsigned short)); // 1.6 MB
  __half* H1     = (__half*)alloc((size_t)Nn * 128 * sizeof(__half));  // 12.8 MB
  __half* H2     = (__half*)alloc((size_t)Nn * 64 * sizeof(__half));   // 6.4 MB
  _Float16* W2h  = (_Float16*)alloc(64 * 128 * sizeof(_Float16));      // 16 KB

  hipMemsetAsync(degi, 0, Nn * sizeof(int), stream);

  const int NGB = (Nn + 15) / 16;           // 3125 node groups (16 nodes each)

  // fused: layer-1 GEMM (H1 = fp16(x@W1)) + degree count (hidden under it)
  k_gemm128_count<<<GT + E2B, 256, 0, stream>>>(x, W1, H1, (const int2*)col,
                                                degi, (ushort2*)rank);
  k_scan1<<<SCAN_B, 1024, 0, stream>>>(degi, rowptr, dis, bsum);
  k_scan3<<<SCAN_B, 1024, 0, stream>>>(rowptr, bsum, W2, W2h);
  k_fill<<<E2B, 256, 0, stream>>>((const int2*)row, (const int2*)col, rowptr,
                                  (const ushort2*)rank, csr);
  // fused: H2 = fp16( relu(agg(H1) + b1) @ W2 )
  k_agg128_gemm64<<<NGB, 256, 0, stream>>>(H1, csr, rowptr, dis, b1, W2h, H2, Nn);
  // layer 2 agg: out = agg(H2) + b2
  k_agg64<<<NGB, 256, 0, stream>>>(H2, csr, rowptr, dis, b2, out, Nn);
}

// Round 2
// 186.491 us; speedup vs baseline: 1.1073x; 1.0521x over previous
//
#include <hip/hip_runtime.h>
#include <hip/hip_fp16.h>

// GCN, N=50000 nodes, E=800000 edges, 128->128(relu)->64, fp32 accum.
// CSR entries are 2B (src only; norm recomputed as dis[src]*dis[v]).
// r12: front-end rebuild based on r11 counters (gemm+count 68us, all pipes
//   idle, 6.45M LDS conflict cycles):
//   (a) k_prep (absorbs degi memset) builds W1h/W2h ONCE in global:
//       fp16, transposed [c][k], XOR-swizzled chunks (chunk (c,k8) at
//       halves c*128 + ((k8^(c&7))<<3)). Was: every gemm block re-read,
//       re-converted, re-transposed 64KB of W1 through a 16-way-conflict
//       b16 LDS write pattern (x782).
//   (b) gemm blocks stage W by LINEAR f16x8 copy (conflict-free) and read
//       B-frags through the swizzle (2 lanes/bank per 16-lane phase).
//   (c) Xs LDS dropped: A-frags loaded global->reg directly (each row read
//       exactly once per block; 16x128B contiguous chunks per wave).
//       LDS 52->32KB => 4 blocks/CU (was 3).
//   (d) edge counting folded INTO the gemm blocks (1024 edges each),
//       issued before the X loads so atomic latency hides under staging
//       (r11's block-split ran count as a serial tail at 3 blocks/CU).
// NOTE (r10 post-mortem): degree-sorted scheduling bought ~0 and its
// counting-sort perm cost 133 us (30 hot atomic addresses serialize).
// Agg kernels sit near the random-gather service floor; natural order kept.

#define Nn 50000
#define Ne 800000
#define NE2 (Ne / 2)                  // 400000 int2 edge pairs
#define SCAN_B ((Nn + 1023) / 1024)   // 49 blocks
#define GT ((Nn + 63) / 64)           // 782 gemm tiles
#define EPB 512                       // int2 edges per gemm block (782*512 >= 400000)

using f16x8 = _Float16 __attribute__((ext_vector_type(8)));
using f32x4 = float __attribute__((ext_vector_type(4)));

// ---------------- prep: zero degi + build swizzled fp16 W images ----------------
// blocks 0..48: degi = 0 (int4 stores). block 49: W1h. block 50: W2h.
// W?h layout: chunk (c, k8) = halves W[k8*8+j][c], j=0..7, stored at
//   halves offset c*128 + ((k8 ^ (c&7)) << 3).  Readers XOR the same way;
//   stagers copy LINEARLY (the swizzle is baked into the global image).
__global__ __launch_bounds__(256) void k_prep(const float* __restrict__ W1,
                                              const float* __restrict__ W2,
                                              _Float16* __restrict__ W1h,
                                              _Float16* __restrict__ W2h,
                                              int* __restrict__ degi) {
  const int b = blockIdx.x, t = threadIdx.x;
  if (b < 49) {
    int i = b * 256 + t;
    if (i < Nn / 4) ((int4*)degi)[i] = make_int4(0, 0, 0, 0);
  } else if (b == 49) {
    // W1: fp32 [k=128][c=128] -> W1h 2048 chunks, 8 per thread
    for (int i = 0; i < 8; ++i) {
      int id = i * 256 + t;
      int c = id & 127, k8 = id >> 7;
      f16x8 hv;
      #pragma unroll
      for (int j = 0; j < 8; ++j) hv[j] = (_Float16)W1[(k8 * 8 + j) * 128 + c];
      *(f16x8*)&W1h[c * 128 + ((k8 ^ (c & 7)) << 3)] = hv;
    }
  } else {
    // W2: fp32 [k=128][c=64] -> W2h 1024 chunks, 4 per thread
    for (int i = 0; i < 4; ++i) {
      int id = i * 256 + t;
      int c = id & 63, k8 = id >> 6;
      f16x8 hv;
      #pragma unroll
      for (int j = 0; j < 8; ++j) hv[j] = (_Float16)W2[(k8 * 8 + j) * 64 + c];
      *(f16x8*)&W2h[c * 128 + ((k8 ^ (c & 7)) << 3)] = hv;
    }
  }
}

// ---------------- FUSED: layer-1 MFMA GEMM + degree count (interleaved) ----------------
// Every block: (1) linear-stage W1h -> LDS (32KB, conflict-free);
// (2) count its 1024-edge slice (atomics overlap staging/X latency);
// (3) A-frags direct global->reg (fp32->fp16 inline); (4) MFMA; (5) store H1.
__global__ __launch_bounds__(256, 4) void k_gemm128_count(
    const float* __restrict__ X, const _Float16* __restrict__ W1h,
    __half* __restrict__ H, const int2* __restrict__ col2,
    int* __restrict__ degi, ushort2* __restrict__ rank2) {
  __shared__ _Float16 Wts[128 * 128];   // swizzled image, linear copy

  const int tid = threadIdx.x;
  const int base = blockIdx.x * 64;

  // stage W1h -> LDS: 2048 x 16B chunks, 8 per thread, fully coalesced
  {
    const f16x8* src = (const f16x8*)W1h;
    f16x8* dst = (f16x8*)Wts;
    #pragma unroll
    for (int i = 0; i < 8; ++i) dst[i * 256 + tid] = src[i * 256 + tid];
  }

  // edge-count slice: 2 int2 per thread; latency hides under staging/X loads
  {
    int i0 = blockIdx.x * EPB + tid;
    int i1 = i0 + 256;
    if (i0 < NE2) {
      int2 c = col2[i0];
      ushort2 rk;
      rk.x = (unsigned short)atomicAdd(&degi[c.x], 1);
      rk.y = (unsigned short)atomicAdd(&degi[c.y], 1);
      rank2[i0] = rk;
    }
    if (i1 < NE2) {
      int2 c = col2[i1];
      ushort2 rk;
      rk.x = (unsigned short)atomicAdd(&degi[c.x], 1);
      rk.y = (unsigned short)atomicAdd(&degi[c.y], 1);
      rank2[i1] = rk;
    }
  }

  // A-fragments direct from global X (each row read exactly once per block)
  const int w = tid >> 6, lane = tid & 63;
  const int quad = lane >> 4, mrow = lane & 15;
  int anode = base + w * 16 + mrow;
  if (anode >= Nn) anode = Nn - 1;
  const float4* xg = (const float4*)(X + (size_t)anode * 128);
  f16x8 av[4];
  #pragma unroll
  for (int ko = 0; ko < 4; ++ko) {
    float4 x0 = xg[ko * 8 + quad * 2];
    float4 x1 = xg[ko * 8 + quad * 2 + 1];
    av[ko][0] = (_Float16)x0.x; av[ko][1] = (_Float16)x0.y;
    av[ko][2] = (_Float16)x0.z; av[ko][3] = (_Float16)x0.w;
    av[ko][4] = (_Float16)x1.x; av[ko][5] = (_Float16)x1.y;
    av[ko][6] = (_Float16)x1.z; av[ko][7] = (_Float16)x1.w;
  }
  __syncthreads();

  f32x4 acc[8];
  #pragma unroll
  for (int ct = 0; ct < 8; ++ct) acc[ct] = (f32x4){0.f, 0.f, 0.f, 0.f};

  #pragma unroll
  for (int ko = 0; ko < 4; ++ko) {
    #pragma unroll
    for (int ct = 0; ct < 8; ++ct) {
      int c = ct * 16 + mrow;
      f16x8 bv = *(const f16x8*)&Wts[c * 128 + (((ko * 4 + quad) ^ (c & 7)) << 3)];
      acc[ct] = __builtin_amdgcn_mfma_f32_16x16x32_f16(av[ko], bv, acc[ct], 0, 0, 0);
    }
  }

  #pragma unroll
  for (int ct = 0; ct < 8; ++ct) {
    #pragma unroll
    for (int r = 0; r < 4; ++r) {
      int node = base + w * 16 + quad * 4 + r;
      if (node < Nn)
        H[(size_t)node * 128 + ct * 16 + mrow] = __float2half(acc[ct][r]);
    }
  }
}

// ---------------- scan phase 1: block-local exclusive scan + dis ----------------
__global__ __launch_bounds__(1024) void k_scan1(const int* __restrict__ degi,
                                                int* __restrict__ rowptr,
                                                float* __restrict__ dis,
                                                int* __restrict__ bsum) {
  __shared__ int wsum[16];
  int tid = threadIdx.x;
  int lane = tid & 63, wid = tid >> 6;
  int i = blockIdx.x * 1024 + tid;
  int v = (i < Nn) ? degi[i] : 0;
  if (i < Nn) dis[i] = rsqrtf((float)(v + 1));   // self-loop adds 1
  int incl = v;
  #pragma unroll
  for (int off = 1; off < 64; off <<= 1) {
    int t = __shfl_up(incl, off);
    if (lane >= off) incl += t;
  }
  if (lane == 63) wsum[wid] = incl;
  __syncthreads();
  if (wid == 0) {
    int wv = (lane < 16) ? wsum[lane] : 0;
    #pragma unroll
    for (int off = 1; off < 16; off <<= 1) {
      int t = __shfl_up(wv, off);
      if (lane >= off) wv += t;
    }
    if (lane < 16) wsum[lane] = wv;  // inclusive over wave totals
  }
  __syncthreads();
  int woff = (wid > 0) ? wsum[wid - 1] : 0;
  if (i < Nn) rowptr[i] = woff + incl - v;       // block-local exclusive
  if (tid == 0) bsum[blockIdx.x] = wsum[15];     // block total
}

// ---------------- scan phase 2+3 fused: each block scans the 49 block sums ----------------
__global__ __launch_bounds__(1024) void k_scan3(int* __restrict__ rowptr,
                                                const int* __restrict__ bsum) {
  __shared__ int off_s;
  int tid = threadIdx.x;
  if (tid < 64) {
    int v = (tid < SCAN_B) ? bsum[tid] : 0;
    int incl = v;
    #pragma unroll
    for (int off = 1; off < 64; off <<= 1) {
      int t = __shfl_up(incl, off);
      if (tid >= off) incl += t;
    }
    if (tid == (int)blockIdx.x) off_s = incl - v;          // exclusive offset
    if (blockIdx.x == 0 && tid == SCAN_B - 1) rowptr[Nn] = incl;  // == Ne
  }
  __syncthreads();
  int i = blockIdx.x * 1024 + tid;
  if (i < Nn) rowptr[i] += off_s;
}

// ---------------- CSR fill: 2B src only, no atomic (2 edges/thread) ----------------
__global__ __launch_bounds__(256) void k_fill(const int2* __restrict__ row2,
                                              const int2* __restrict__ col2,
                                              const int* __restrict__ rowptr,
                                              const ushort2* __restrict__ rank2,
                                              unsigned short* __restrict__ csr) {
  int t = blockIdx.x * 256 + threadIdx.x;
  if (t >= NE2) return;
  int2 r = row2[t];
  int2 c = col2[t];
  ushort2 k = rank2[t];
  csr[rowptr[c.x] + (int)k.x] = (unsigned short)r.x;
  csr[rowptr[c.y] + (int)k.y] = (unsigned short)r.y;
}

__device__ __forceinline__ float2 h2f(unsigned int u) {
  return __half22float2(*(const __half2*)&u);
}

// ---------------- FUSED: agg128(+b1, relu) -> LDS fp16 -> MFMA @ W2 -> H2 fp16 ----------------
// Stage A (agg): 4 nodes/wave, 16 lanes/node, uint4 (8 fp16 feats)/lane.
//   Software-pipelined csr loads (prefetch batch n+1's srcs under batch n's
//   gathers). Stage B: 16x64 MFMA against swizzled W2 image (linear stage).
// Nn = 50000 = 3125 * 16 exactly -> no partial blocks.
__global__ __launch_bounds__(256) void k_agg128_gemm64(
    const __half* __restrict__ H, const unsigned short* __restrict__ csr,
    const int* __restrict__ rowptr, const float* __restrict__ dis,
    const float* __restrict__ bias, const _Float16* __restrict__ W2h,
    __half* __restrict__ H2, int n) {
  __shared__ _Float16 Wts[64 * 128];   // swizzled W2 image (16KB, linear copy)
  __shared__ _Float16 Hs[16 * 136];    // block's 16 aggregated rows (fp16)

  const int tid = threadIdx.x;
  const int wid = tid >> 6, lane = tid & 63;
  const int sub = lane >> 4, fl = lane & 15;
  const int nb = wid * 4 + sub;                  // node-in-block [0,16)
  const int v = blockIdx.x * 16 + nb;

  // stage W2h -> LDS: 1024 x 16B chunks, linear, conflict-free
  {
    const f16x8* src = (const f16x8*)W2h;
    f16x8* dst = (f16x8*)Wts;
    #pragma unroll
    for (int i = 0; i < 4; ++i) dst[i * 256 + tid] = src[i * 256 + tid];
  }

  // ---- stage A: aggregate node v's 8 feats per lane ----
  int s = rowptr[v], e = rowptr[v + 1];
  float d = dis[v];
  float sw = d * d;                              // self-loop norm = 1/deg
  const uint4* Hq = (const uint4*)H;             // 16 uint4 per 256B row
  uint4 hv = Hq[(size_t)v * 16 + fl];
  float2 p0 = h2f(hv.x), p1 = h2f(hv.y), p2 = h2f(hv.z), p3 = h2f(hv.w);
  float a0 = p0.x * sw, a1 = p0.y * sw, a2 = p1.x * sw, a3 = p1.y * sw;
  float a4 = p2.x * sw, a5 = p2.y * sw, a6 = p3.x * sw, a7 = p3.y * sw;
  constexpr int D = 6;
  if (s < e) {
    int srcs[D];
    #pragma unroll
    for (int j = 0; j < D; ++j) {
      int idx = s + j;
      srcs[j] = csr[(idx < e) ? idx : (e - 1)];
    }
    for (int base = s; base < e; base += D) {
      uint4 q[D];
      float wd[D];
      #pragma unroll
      for (int j = 0; j < D; ++j) q[j] = Hq[(size_t)srcs[j] * 16 + fl];
      #pragma unroll
      for (int j = 0; j < D; ++j) wd[j] = dis[srcs[j]];
      int ns[D];                                 // prefetch next batch srcs
      #pragma unroll
      for (int j = 0; j < D; ++j) {
        int idx = base + D + j;
        ns[j] = csr[(idx < e) ? idx : (e - 1)];
      }
      #pragma unroll
      for (int j = 0; j < D; ++j) {
        float w = ((base + j) < e) ? wd[j] * d : 0.f;
        float2 t;
        t = h2f(q[j].x); a0 = fmaf(w, t.x, a0); a1 = fmaf(w, t.y, a1);
        t = h2f(q[j].y); a2 = fmaf(w, t.x, a2); a3 = fmaf(w, t.y, a3);
        t = h2f(q[j].z); a4 = fmaf(w, t.x, a4); a5 = fmaf(w, t.y, a5);
        t = h2f(q[j].w); a6 = fmaf(w, t.x, a6); a7 = fmaf(w, t.y, a7);
      }
      #pragma unroll
      for (int j = 0; j < D; ++j) srcs[j] = ns[j];
    }
  }
  // +b1, relu, fp16 -> LDS row nb
  {
    const float4* Bq = (const float4*)bias;
    float4 b0 = Bq[fl * 2], b1v = Bq[fl * 2 + 1];
    f16x8 hrow;
    hrow[0] = (_Float16)fmaxf(a0 + b0.x, 0.f);
    hrow[1] = (_Float16)fmaxf(a1 + b0.y, 0.f);
    hrow[2] = (_Float16)fmaxf(a2 + b0.z, 0.f);
    hrow[3] = (_Float16)fmaxf(a3 + b0.w, 0.f);
    hrow[4] = (_Float16)fmaxf(a4 + b1v.x, 0.f);
    hrow[5] = (_Float16)fmaxf(a5 + b1v.y, 0.f);
    hrow[6] = (_Float16)fmaxf(a6 + b1v.z, 0.f);
    hrow[7] = (_Float16)fmaxf(a7 + b1v.w, 0.f);
    *(f16x8*)&Hs[nb * 136 + fl * 8] = hrow;
  }
  __syncthreads();

  // ---- stage B: 16x64 = (16x128) @ (128x64), wave w -> cols [w*16, w*16+16) ----
  const int quad = lane >> 4, mrow = lane & 15;
  f32x4 acc = (f32x4){0.f, 0.f, 0.f, 0.f};
  const int c = wid * 16 + mrow;
  #pragma unroll
  for (int ko = 0; ko < 4; ++ko) {
    f16x8 avx = *(const f16x8*)&Hs[mrow * 136 + ko * 32 + quad * 8];
    f16x8 bv = *(const f16x8*)&Wts[c * 128 + (((ko * 4 + quad) ^ (c & 7)) << 3)];
    acc = __builtin_amdgcn_mfma_f32_16x16x32_f16(avx, bv, acc, 0, 0, 0);
  }
  #pragma unroll
  for (int r = 0; r < 4; ++r) {
    int node = blockIdx.x * 16 + quad * 4 + r;
    if (node < n)
      H2[(size_t)node * 64 + wid * 16 + mrow] = __float2half(acc[r]);
  }
}

// ---------------- aggregate 64 feats (+bias, no relu) ----------------
// 4 nodes/wave, 16 lanes/node, uint2 (4 feats) per lane; depth-8 batches,
// software-pipelined csr loads (same scheme as agg128).
__global__ __launch_bounds__(256) void k_agg64(const __half* __restrict__ H,
                                               const unsigned short* __restrict__ csr,
                                               const int* __restrict__ rowptr,
                                               const float* __restrict__ dis,
                                               const float* __restrict__ bias,
                                               float* __restrict__ Out, int n) {
  const int wid = threadIdx.x >> 6, lane = threadIdx.x & 63;
  const int sub = lane >> 4, fl = lane & 15;
  int v = blockIdx.x * 16 + wid * 4 + sub;
  if (v >= n) return;
  int s = rowptr[v], e = rowptr[v + 1];
  float d = dis[v];
  float sw = d * d;
  const uint2* Hq = (const uint2*)H;             // 16 uint2 per 128B row
  uint2 hv = Hq[(size_t)v * 16 + fl];
  float2 p0 = h2f(hv.x), p1 = h2f(hv.y);
  float a0 = p0.x * sw, a1 = p0.y * sw, a2 = p1.x * sw, a3 = p1.y * sw;
  constexpr int D = 8;
  if (s < e) {
    int srcs[D];
    #pragma unroll
    for (int j = 0; j < D; ++j) {
      int idx = s + j;
      srcs[j] = csr[(idx < e) ? idx : (e - 1)];
    }
    for (int base = s; base < e; base += D) {
      uint2 q[D];
      float wd[D];
      #pragma unroll
      for (int j = 0; j < D; ++j) q[j] = Hq[(size_t)srcs[j] * 16 + fl];
      #pragma unroll
      for (int j = 0; j < D; ++j) wd[j] = dis[srcs[j]];
      int ns[D];                                 // prefetch next batch srcs
      #pragma unroll
      for (int j = 0; j < D; ++j) {
        int idx = base + D + j;
        ns[j] = csr[(idx < e) ? idx : (e - 1)];
      }
      #pragma unroll
      for (int j = 0; j < D; ++j) {
        float w = ((base + j) < e) ? wd[j] * d : 0.f;
        float2 t;
        t = h2f(q[j].x); a0 = fmaf(w, t.x, a0); a1 = fmaf(w, t.y, a1);
        t = h2f(q[j].y); a2 = fmaf(w, t.x, a2); a3 = fmaf(w, t.y, a3);
      }
      #pragma unroll
      for (int j = 0; j < D; ++j) srcs[j] = ns[j];
    }
  }
  const float4* Bq = (const float4*)bias;
  float4 b = Bq[fl];
  float4 o = make_float4(a0 + b.x, a1 + b.y, a2 + b.z, a3 + b.w);
  ((float4*)(Out + (size_t)v * 64))[fl] = o;
}

extern "C" void kernel_launch(void* const* d_in, const int* in_sizes, int n_in,
                              void* d_out, int out_size, void* d_ws, size_t ws_size,
                              hipStream_t stream) {
  const float* x  = (const float*)d_in[0];
  const int*   ei = (const int*)d_in[1];    // [2, E] row-major
  const int*   row = ei;                    // edge_index[0] (source)
  const int*   col = ei + Ne;               // edge_index[1] (dest / segment)
  const float* W1 = (const float*)d_in[2];
  const float* b1 = (const float*)d_in[3];
  const float* W2 = (const float*)d_in[4];
  const float* b2 = (const float*)d_in[5];
  float* out = (float*)d_out;

  char* ws = (char*)d_ws;
  size_t off = 0;
  auto alloc = [&](size_t bytes) -> void* {
    void* p = ws + off;
    off += (bytes + 255) & ~(size_t)255;
    return p;
  };
  int*    degi   = (int*)   alloc(Nn * sizeof(int));       // zeroed by k_prep
  int*    rowptr = (int*)   alloc((Nn + 1) * sizeof(int));
  float*  dis    = (float*) alloc(Nn * sizeof(float));
  int*    bsum   = (int*)   alloc(64 * sizeof(int));
  unsigned short* rank = (unsigned short*)alloc((size_t)Ne * sizeof(unsigned short)); // 1.6 MB
  unsigned short* csr  = (unsigned short*)alloc((size_t)Ne * sizeof(unsigned short)); // 1.6 MB
  __half* H1     = (__half*)alloc((size_t)Nn * 128 * sizeof(__half));  // 12.8 MB
  __half* H2     = (__half*)alloc((size_t)Nn * 64 * sizeof(__half));   // 6.4 MB
  _Float16* W1h  = (_Float16*)alloc(128 * 128 * sizeof(_Float16));     // 32 KB
  _Float16* W2h  = (_Float16*)alloc(64 * 128 * sizeof(_Float16));      // 16 KB

  const int NGB = (Nn + 15) / 16;           // 3125 node groups (16 nodes each)
  const int E1B = (NE2 + 255) / 256;        // 1563 fill blocks

  // prep: degi=0 + swizzled fp16 W images (replaces hipMemsetAsync)
  k_prep<<<51, 256, 0, stream>>>(W1, W2, W1h, W2h, degi);
  // fused: layer-1 GEMM (H1 = fp16(x@W1)) + degree count (overlapped)
  k_gemm128_count<<<GT, 256, 0, stream>>>(x, W1h, H1, (const int2*)col,
                                          degi, (ushort2*)rank);
  k_scan1<<<SCAN_B, 1024, 0, stream>>>(degi, rowptr, dis, bsum);
  k_scan3<<<SCAN_B, 1024, 0, stream>>>(rowptr, bsum);
  k_fill<<<E1B, 256, 0, stream>>>((const int2*)row, (const int2*)col, rowptr,
                                  (const ushort2*)rank, csr);
  // fused: H2 = fp16( relu(agg(H1) + b1) @ W2 )
  k_agg128_gemm64<<<NGB, 256, 0, stream>>>(H1, csr, rowptr, dis, b1, W2h, H2, Nn);
  // layer 2 agg: out = agg(H2) + b2
  k_agg64<<<NGB, 256, 0, stream>>>(H2, csr, rowptr, dis, b2, out, Nn);
}